// Round 7
// baseline (152.377 us; speedup 1.0000x reference)
//
#include <hip/hip_runtime.h>
#include <hip/hip_cooperative_groups.h>

namespace cg = cooperative_groups;

#define E 8192
#define NNODE 2048
#define C 128
#define CAPN 32      // max stored edges per node (Poisson(8) tail; P(>32) ~ 1e-13)
#define RPB 16       // GEMM rows per block (4 per wave)
#define NBLK (E / RPB)   // 512 blocks

typedef unsigned int u32;
typedef unsigned long long u64;

// Single cooperative dispatch, three phases:
//  P0: zero cnt (blocks 0-7), pack edges (blocks 0-31), h = x@W + bias,
//      attention dots a_src/a_dst.  [grid.sync]
//  P1: inverted node->edge index, one parallel atomic round.  [grid.sync]
//  P2: per-edge sparse softmax-aggregate, 4 edges per wave.
__global__ __launch_bounds__(256, 2) void gat_fused(
    const float* __restrict__ x, const float* __restrict__ W,
    const float* __restrict__ att_s, const float* __restrict__ att_d,
    const float* __restrict__ bias, const int* __restrict__ ei,
    float* __restrict__ h, float* __restrict__ asrc, float* __restrict__ adst,
    int* __restrict__ packed, int* __restrict__ cnt, int* __restrict__ nlist,
    float* __restrict__ out)
{
    cg::grid_group grid = cg::this_grid();
    const int tid = threadIdx.x, lane = tid & 63, wv = tid >> 6;
    const int bid = (int)blockIdx.x;

    __shared__ __align__(16) float xs[RPB * C];   // 8 KB
    __shared__ float2 lst[4][64];                 // 2 KB

    // ---------------- Phase 0 ----------------
    if (bid < NNODE / 256) cnt[bid * 256 + tid] = 0;

    int es = 0, ed = 0;
    const int g = bid * 256 + tid;
    const bool has_edge = g < E;     // blocks 0..31
    if (has_edge) {
        es = ei[g]; ed = ei[E + g];
        packed[g] = (es << 16) | ed;
    }

    const int row0 = bid * RPB;
    {   // stage x rows once (512 float4, 2 per thread)
        const float4* xg = reinterpret_cast<const float4*>(x + (size_t)row0 * C);
        float4* xsv = reinterpret_cast<float4*>(xs);
        xsv[tid]       = xg[tid];
        xsv[tid + 256] = xg[tid + 256];
    }
    __syncthreads();

    float a0x = 0.f, a0y = 0.f, a1x = 0.f, a1y = 0.f;
    float a2x = 0.f, a2y = 0.f, a3x = 0.f, a3y = 0.f;
    const float4* xp0 = reinterpret_cast<const float4*>(xs + (wv * 4 + 0) * C);
    const float4* xp1 = reinterpret_cast<const float4*>(xs + (wv * 4 + 1) * C);
    const float4* xp2 = reinterpret_cast<const float4*>(xs + (wv * 4 + 2) * C);
    const float4* xp3 = reinterpret_cast<const float4*>(xs + (wv * 4 + 3) * C);
    const float* Wc = W + 2 * lane;

#define ROWFMA(V, AX, AY)                                    \
    AX = fmaf(V.x, w0.x, AX); AY = fmaf(V.x, w0.y, AY);      \
    AX = fmaf(V.y, w1.x, AX); AY = fmaf(V.y, w1.y, AY);      \
    AX = fmaf(V.z, w2.x, AX); AY = fmaf(V.z, w2.y, AY);      \
    AX = fmaf(V.w, w3.x, AX); AY = fmaf(V.w, w3.y, AY);
    for (int k4 = 0; k4 < C / 4; ++k4) {
        const float4 v0 = xp0[k4], v1 = xp1[k4], v2 = xp2[k4], v3 = xp3[k4];
        const float2 w0 = *reinterpret_cast<const float2*>(Wc + (4 * k4 + 0) * C);
        const float2 w1 = *reinterpret_cast<const float2*>(Wc + (4 * k4 + 1) * C);
        const float2 w2 = *reinterpret_cast<const float2*>(Wc + (4 * k4 + 2) * C);
        const float2 w3 = *reinterpret_cast<const float2*>(Wc + (4 * k4 + 3) * C);
        ROWFMA(v0, a0x, a0y) ROWFMA(v1, a1x, a1y)
        ROWFMA(v2, a2x, a2y) ROWFMA(v3, a3x, a3y)
    }
#undef ROWFMA

    {
        const float2 asv = *reinterpret_cast<const float2*>(att_s + 2 * lane);
        const float2 adv = *reinterpret_cast<const float2*>(att_d + 2 * lane);
        const float2 bv  = *reinterpret_cast<const float2*>(bias  + 2 * lane);
        const int rw0 = row0 + wv * 4;
#define EPI(R, AX, AY) {                                                        \
    *reinterpret_cast<float2*>(&h[(size_t)(rw0 + R) * C + 2 * lane]) =          \
        make_float2(AX + bv.x, AY + bv.y);  /* bias folded into h */            \
    float ps = fmaf(AX, asv.x, AY * asv.y);                                     \
    float pd = fmaf(AX, adv.x, AY * adv.y);                                     \
    _Pragma("unroll")                                                           \
    for (int off = 32; off > 0; off >>= 1) {                                    \
        ps += __shfl_xor(ps, off); pd += __shfl_xor(pd, off);                   \
    }                                                                           \
    if (lane == 0) { asrc[rw0 + R] = ps; adst[rw0 + R] = pd; } }
        EPI(0, a0x, a0y) EPI(1, a1x, a1y) EPI(2, a2x, a2y) EPI(3, a3x, a3y)
#undef EPI
    }

    grid.sync();

    // ---------------- Phase 1: index insert (one parallel round) ----------------
    if (has_edge) {
        int slot = atomicAdd(&cnt[es], 1);
        if (slot < CAPN) nlist[es * CAPN + slot] = g;
        if (ed != es) {
            slot = atomicAdd(&cnt[ed], 1);
            if (slot < CAPN) nlist[ed * CAPN + slot] = g;
        }
    }

    grid.sync();

    // ---------------- Phase 2: aggregate, 4 edges per wave ----------------
    const int wgid = bid * 4 + wv;          // 0..2047
    for (int e4 = 0; e4 < 4; ++e4) {
        const int i = wgid * 4 + e4;        // 0..8191

        const u32 pi = (u32)packed[i];
        const int si = (int)(pi >> 16), di = (int)(pi & 0xffffu);
        const float adi = adst[i];
        int len_s = cnt[si]; if (len_s > CAPN) len_s = CAPN;
        int len_d = (di == si) ? 0 : cnt[di]; if (len_d > CAPN) len_d = CAPN;
        const int ntot = len_s + len_d;     // <= 64

        int key = 0x7fffffff;
        float sc = -INFINITY;
        bool valid = false;
        if (lane < ntot) {
            const bool from_s = lane < len_s;
            const int j = nlist[(from_s ? si : di) * CAPN + (from_s ? lane : lane - len_s)];
            const u32 pj = (u32)packed[j];
            valid = from_s || ((int)(pj >> 16) != si && (int)(pj & 0xffffu) != si);
            if (valid) {
                const float s0 = adi + asrc[j];
                sc = s0 >= 0.f ? s0 : 0.2f * s0;
                key = j;
            }
        }

        // exact row max + valid count (order-independent)
        float m = sc;
        #pragma unroll
        for (int off = 32; off > 0; off >>= 1) m = fmaxf(m, __shfl_xor(m, off));
        const int nvalid = (int)__popcll(__ballot(valid));

        float p = __expf(sc - m);   // invalid lanes: exp(-inf) = 0 exactly

        // bitonic sort ascending by edge id -> canonical deterministic order
        #pragma unroll
        for (int k = 2; k <= 64; k <<= 1) {
            #pragma unroll
            for (int st = k >> 1; st > 0; st >>= 1) {
                const int   ok = __shfl_xor(key, st);
                const float op = __shfl_xor(p, st);
                const bool takeMin = ((lane & k) == 0) == ((lane & st) == 0);
                if (takeMin ? (ok < key) : (ok > key)) { key = ok; p = op; }
            }
        }
        lst[wv][lane] = make_float2(__int_as_float(key == 0x7fffffff ? i : key), p);

        // 4-wide weighted gather; padded tail has p=0 (exact no-op)
        const int nch = (nvalid + 3) >> 2;
        float lsum = 0.f, o0 = 0.f, o1 = 0.f;
        const float* hb = h + 2 * lane;
        for (int t = 0; t < nch; ++t) {
            const float2 e0 = lst[wv][4 * t + 0];
            const float2 e1 = lst[wv][4 * t + 1];
            const float2 e2 = lst[wv][4 * t + 2];
            const float2 e3 = lst[wv][4 * t + 3];
            const float2 h0 = *reinterpret_cast<const float2*>(hb + (size_t)__float_as_int(e0.x) * C);
            const float2 h1 = *reinterpret_cast<const float2*>(hb + (size_t)__float_as_int(e1.x) * C);
            const float2 h2 = *reinterpret_cast<const float2*>(hb + (size_t)__float_as_int(e2.x) * C);
            const float2 h3 = *reinterpret_cast<const float2*>(hb + (size_t)__float_as_int(e3.x) * C);
            lsum += (e0.y + e1.y) + (e2.y + e3.y);
            o0 = fmaf(e0.y, h0.x, o0); o1 = fmaf(e0.y, h0.y, o1);
            o0 = fmaf(e1.y, h1.x, o0); o1 = fmaf(e1.y, h1.y, o1);
            o0 = fmaf(e2.y, h2.x, o0); o1 = fmaf(e2.y, h2.y, o1);
            o0 = fmaf(e3.y, h3.x, o0); o1 = fmaf(e3.y, h3.y, o1);
        }
        const float inv = 1.0f / lsum;  // h includes bias; sum(alpha)=1 recovers +bias
        *reinterpret_cast<float2*>(&out[(size_t)i * C + 2 * lane]) =
            make_float2(o0 * inv, o1 * inv);
    }
}

extern "C" void kernel_launch(void* const* d_in, const int* in_sizes, int n_in,
                              void* d_out, int out_size, void* d_ws, size_t ws_size,
                              hipStream_t stream) {
    const float* x     = (const float*)d_in[0];
    const int*   ei    = (const int*)d_in[1];
    const float* W     = (const float*)d_in[2];
    const float* att_s = (const float*)d_in[3];
    const float* att_d = (const float*)d_in[4];
    const float* bias  = (const float*)d_in[5];

    float* h      = (float*)d_ws;                 // 4 MB
    float* asrc   = h + (size_t)E * C;            // 32 KB
    float* adst   = asrc + E;                     // 32 KB
    int*   packed = (int*)(adst + E);             // 32 KB
    int*   cnt    = packed + E;                   // 8 KB
    int*   nlist  = cnt + NNODE;                  // 256 KB
    float* out    = (float*)d_out;

    void* args[13];
    args[0]  = (void*)&x;      args[1]  = (void*)&W;
    args[2]  = (void*)&att_s;  args[3]  = (void*)&att_d;
    args[4]  = (void*)&bias;   args[5]  = (void*)&ei;
    args[6]  = (void*)&h;      args[7]  = (void*)&asrc;
    args[8]  = (void*)&adst;   args[9]  = (void*)&packed;
    args[10] = (void*)&cnt;    args[11] = (void*)&nlist;
    args[12] = (void*)&out;

    hipLaunchCooperativeKernel((const void*)gat_fused, dim3(NBLK), dim3(256),
                               args, 0, stream);
}

// Round 8
// 38.323 us; speedup vs baseline: 3.9761x; 3.9761x over previous
//
#include <hip/hip_runtime.h>

#define E 8192
#define NNODE 2048
#define C 128
#define CAPN 32   // max stored edges per node (Poisson(8) tail; P(deg>32) ~ 1e-13)

typedef unsigned int u32;
typedef unsigned long long u64;

// Kernel 1: h = x@W (f32), a_src/a_dst dots, packed endpoints, and inverted
// node->edge index via atomic slot placement (order canonicalized later).
// 256 threads = 4 waves; each wave computes 4 rows. grid = E/16 = 512.
__global__ __launch_bounds__(256) void gat_prep(
    const float* __restrict__ x, const float* __restrict__ W,
    const float* __restrict__ att_s, const float* __restrict__ att_d,
    const int* __restrict__ ei,
    float* __restrict__ h, float* __restrict__ asrc, float* __restrict__ adst,
    int* __restrict__ packed, int* __restrict__ cnt, int* __restrict__ nlist)
{
    const int tid = threadIdx.x, lane = tid & 63, wv = tid >> 6;
    const int g = blockIdx.x * 256 + tid;
    if (g < E) {  // block-uniform predicate (blocks 0..31)
        const int s = ei[g], d = ei[E + g];
        packed[g] = (s << 16) | d;
        int slot = atomicAdd(&cnt[s], 1);
        if (slot < CAPN) nlist[s * CAPN + slot] = g;
        if (d != s) {
            slot = atomicAdd(&cnt[d], 1);
            if (slot < CAPN) nlist[d * CAPN + slot] = g;
        }
    }

    const int row0 = blockIdx.x * 16 + wv * 4;
    __shared__ __align__(16) float xs[4][4][C];
    #pragma unroll
    for (int r = 0; r < 4; ++r)
        *reinterpret_cast<float2*>(&xs[wv][r][2 * lane]) =
            *reinterpret_cast<const float2*>(&x[(size_t)(row0 + r) * C + 2 * lane]);
    __syncthreads();

    float a00 = 0.f, a01 = 0.f, a10 = 0.f, a11 = 0.f;
    float a20 = 0.f, a21 = 0.f, a30 = 0.f, a31 = 0.f;
    const float4* xp0 = reinterpret_cast<const float4*>(xs[wv][0]);
    const float4* xp1 = reinterpret_cast<const float4*>(xs[wv][1]);
    const float4* xp2 = reinterpret_cast<const float4*>(xs[wv][2]);
    const float4* xp3 = reinterpret_cast<const float4*>(xs[wv][3]);
    const float* Wc = W + 2 * lane;

#define ROWFMA(V, A0, A1)                                    \
    A0 = fmaf(V.x, w0.x, A0); A1 = fmaf(V.x, w0.y, A1);      \
    A0 = fmaf(V.y, w1.x, A0); A1 = fmaf(V.y, w1.y, A1);      \
    A0 = fmaf(V.z, w2.x, A0); A1 = fmaf(V.z, w2.y, A1);      \
    A0 = fmaf(V.w, w3.x, A0); A1 = fmaf(V.w, w3.y, A1);

    for (int k4 = 0; k4 < C / 4; ++k4) {
        const float4 v0 = xp0[k4], v1 = xp1[k4], v2 = xp2[k4], v3 = xp3[k4];
        const float2 w0 = *reinterpret_cast<const float2*>(Wc + (4 * k4 + 0) * C);
        const float2 w1 = *reinterpret_cast<const float2*>(Wc + (4 * k4 + 1) * C);
        const float2 w2 = *reinterpret_cast<const float2*>(Wc + (4 * k4 + 2) * C);
        const float2 w3 = *reinterpret_cast<const float2*>(Wc + (4 * k4 + 3) * C);
        ROWFMA(v0, a00, a01)
        ROWFMA(v1, a10, a11)
        ROWFMA(v2, a20, a21)
        ROWFMA(v3, a30, a31)
    }
#undef ROWFMA

    const float2 asv = *reinterpret_cast<const float2*>(att_s + 2 * lane);
    const float2 adv = *reinterpret_cast<const float2*>(att_d + 2 * lane);
#define EPI(R, A0, A1) {                                                        \
    *reinterpret_cast<float2*>(&h[(size_t)(row0 + R) * C + 2 * lane]) =         \
        make_float2(A0, A1);                                                    \
    float ps = fmaf(A0, asv.x, A1 * asv.y);                                     \
    float pd = fmaf(A0, adv.x, A1 * adv.y);                                     \
    _Pragma("unroll")                                                           \
    for (int off = 32; off > 0; off >>= 1) {                                    \
        ps += __shfl_xor(ps, off); pd += __shfl_xor(pd, off);                   \
    }                                                                           \
    if (lane == 0) { asrc[row0 + R] = ps; adst[row0 + R] = pd; } }
    EPI(0, a00, a01)
    EPI(1, a10, a11)
    EPI(2, a20, a21)
    EPI(3, a30, a31)
#undef EPI
}

// Kernel 2: one wave per target edge i. Candidates = nlist[s_i] ++ nlist[d_i]
// (<= 64 with CAPN=32), one per lane. Dedup: j from the d-list counts only if
// j is NOT incident to s_i. Bitonic-sort candidates by edge id -> canonical,
// bit-deterministic summation order. Then softmax + h-row gather (lane = 2 ch).
__global__ __launch_bounds__(256) void gat_aggr(
    const int* __restrict__ packed, const float* __restrict__ h,
    const float* __restrict__ asrc, const float* __restrict__ adst,
    const float* __restrict__ bias,
    const int* __restrict__ cnt, const int* __restrict__ nlist,
    float* __restrict__ out)
{
    __shared__ float2 lst[4][64];
    const int tid = threadIdx.x, lane = tid & 63, wv = tid >> 6;
    const int i = blockIdx.x * 4 + wv;

    const u32 pi = (u32)packed[i];
    const u32 si = pi >> 16, di = pi & 0xffffu;
    const float adi = adst[i];
    int len_s = cnt[si]; if (len_s > CAPN) len_s = CAPN;
    int len_d = (di == si) ? 0 : cnt[di]; if (len_d > CAPN) len_d = CAPN;
    const int ntot = len_s + len_d;  // <= 64

    int key = 0x7fffffff, jg = 0;
    float sc = -INFINITY;
    bool valid = false;
    if (lane < ntot) {
        const bool from_s = lane < len_s;
        const int idx = from_s ? ((int)si * CAPN + lane)
                               : ((int)di * CAPN + (lane - len_s));
        const int j = nlist[idx];
        const u32 pj = (u32)packed[j];
        valid = from_s || ((pj >> 16) != si && (pj & 0xffffu) != si);
        if (valid) {
            const float s0 = adi + asrc[j];
            sc = s0 >= 0.f ? s0 : 0.2f * s0;
            key = j; jg = j;
        }
    }

    // row max + valid count (order-independent)
    float m = sc;
    #pragma unroll
    for (int off = 32; off > 0; off >>= 1) m = fmaxf(m, __shfl_xor(m, off));
    const int nvalid = (int)__popcll(__ballot(valid));

    // bitonic sort ascending by key (valid edge ids unique; invalid = INT_MAX ties)
    #pragma unroll
    for (int k = 2; k <= 64; k <<= 1) {
        #pragma unroll
        for (int st = k >> 1; st > 0; st >>= 1) {
            const int   ok = __shfl_xor(key, st);
            const int   oj = __shfl_xor(jg, st);
            const float os = __shfl_xor(sc, st);
            const bool takeMin = ((lane & k) == 0) == ((lane & st) == 0);
            const bool takeOther = takeMin ? (ok < key) : (ok > key);
            if (takeOther) { key = ok; jg = oj; sc = os; }
        }
    }
    lst[wv][lane] = make_float2(__int_as_float(jg), sc);

    // softmax weights + weighted sum of h rows (valid entries are lst[0..nvalid))
    float lsum = 0.f, o0 = 0.f, o1 = 0.f;
    for (int t = 0; t < nvalid; ++t) {
        const float2 e = lst[wv][t];
        const float p = __expf(e.y - m);
        const int j = __float_as_int(e.x);
        lsum += p;
        const float2 hv = *reinterpret_cast<const float2*>(&h[(size_t)j * C + 2 * lane]);
        o0 = fmaf(p, hv.x, o0);
        o1 = fmaf(p, hv.y, o1);
    }
    const float inv = 1.0f / lsum;
    const float2 bv = *reinterpret_cast<const float2*>(bias + 2 * lane);
    *reinterpret_cast<float2*>(&out[(size_t)i * C + 2 * lane]) =
        make_float2(fmaf(o0, inv, bv.x), fmaf(o1, inv, bv.y));
}

extern "C" void kernel_launch(void* const* d_in, const int* in_sizes, int n_in,
                              void* d_out, int out_size, void* d_ws, size_t ws_size,
                              hipStream_t stream) {
    const float* x     = (const float*)d_in[0];
    const int*   ei    = (const int*)d_in[1];
    const float* W     = (const float*)d_in[2];
    const float* att_s = (const float*)d_in[3];
    const float* att_d = (const float*)d_in[4];
    const float* bias  = (const float*)d_in[5];

    float* h      = (float*)d_ws;                 // 4 MB
    float* asrc   = h + (size_t)E * C;            // 32 KB
    float* adst   = asrc + E;                     // 32 KB
    int*   packed = (int*)(adst + E);             // 32 KB
    int*   cnt    = packed + E;                   // 8 KB
    int*   nlist  = cnt + NNODE;                  // 256 KB

    hipMemsetAsync(cnt, 0, NNODE * sizeof(int), stream);
    gat_prep<<<E / 16, 256, 0, stream>>>(x, W, att_s, att_d, ei,
                                         h, asrc, adst, packed, cnt, nlist);
    gat_aggr<<<E / 4, 256, 0, stream>>>(packed, h, asrc, adst, bias,
                                        cnt, nlist, (float*)d_out);
}